// Round 1
// baseline (155.541 us; speedup 1.0000x reference)
//
#include <hip/hip_runtime.h>

// Problem constants (B=4, S=2048, D=1024, O=1024, C=8)
#define TOK   8192
#define DIM   1024
#define OUTD  1024
#define NCAT  8
#define BM    128
#define BN    128
#define BK    32
#define MAX_MT 71                 // worst-case m-tiles: 7 cats * 1 token + 1 cat rest
#define MPMAX (MAX_MT * BM)       // 9088 padded rows

typedef __attribute__((ext_vector_type(8))) __bf16 bf16x8;
typedef __attribute__((ext_vector_type(4))) float  f32x4;

__device__ __forceinline__ unsigned short f2bf(float f) {
  unsigned u = __float_as_uint(f);
  u += 0x7fffu + ((u >> 16) & 1u);      // RNE, fine for non-NaN inputs
  return (unsigned short)(u >> 16);
}

// ---------------- K1: bucket tokens by category, build tile table ----------
__global__ __launch_bounds__(1024) void k_build(const int* __restrict__ cid,
    int* __restrict__ row_token, int* __restrict__ tile_c, int* __restrict__ tile_m) {
  __shared__ int cnt[NCAT], gbase[NCAT], pos[NCAT];
  int tid = threadIdx.x;
  if (tid < NCAT) { cnt[tid] = 0; pos[tid] = 0; }
  __syncthreads();
  for (int t = tid; t < TOK; t += 1024) atomicAdd(&cnt[cid[t]], 1);
  __syncthreads();
  if (tid == 0) {
    int mt = 0, pr = 0;
    for (int c = 0; c < NCAT; ++c) {
      gbase[c] = pr;
      int nt = (cnt[c] + BM - 1) / BM;
      for (int i = 0; i < nt; ++i) { tile_c[mt] = c; tile_m[mt] = pr + i * BM; ++mt; }
      pr += nt * BM;
    }
    for (; mt < MAX_MT; ++mt) { tile_c[mt] = -1; tile_m[mt] = 0; }
  }
  __syncthreads();
  for (int r = tid; r < MPMAX; r += 1024) row_token[r] = -1;
  __syncthreads();
  for (int t = tid; t < TOK; t += 1024) {
    int c = cid[t];
    int p = atomicAdd(&pos[c], 1);
    row_token[gbase[c] + p] = t;
  }
}

// ---------------- K2a: gather + fp32->bf16 convert x into bucketed layout --
__global__ __launch_bounds__(256) void k_gather_x(const float* __restrict__ x,
    const int* __restrict__ row_token, unsigned short* __restrict__ xg) {
  int idx = blockIdx.x * 256 + threadIdx.x;   // one thread per 8 elements
  int r  = idx >> 7;
  int e0 = (idx & 127) << 3;
  if (r >= MPMAX) return;
  int tok = row_token[r];
  union { unsigned short u[8]; uint4 v; } o;
  if (tok >= 0) {
    const float4* s = (const float4*)(x + (size_t)tok * DIM + e0);
    float4 a = s[0], b = s[1];
    o.u[0] = f2bf(a.x); o.u[1] = f2bf(a.y); o.u[2] = f2bf(a.z); o.u[3] = f2bf(a.w);
    o.u[4] = f2bf(b.x); o.u[5] = f2bf(b.y); o.u[6] = f2bf(b.z); o.u[7] = f2bf(b.w);
  } else {
    o.v = make_uint4(0u, 0u, 0u, 0u);
  }
  *(uint4*)(xg + (size_t)r * DIM + e0) = o.v;
}

// ---------------- K2b: transpose + convert weight -> wt[c][o][d] bf16 ------
__global__ __launch_bounds__(256) void k_conv_w(const float* __restrict__ w,
    unsigned short* __restrict__ wt) {
  int c = blockIdx.z, dt = blockIdx.y, ot = blockIdx.x;   // 64x64 tiles
  __shared__ unsigned short t[64][72];                    // 72: rows stay 16B-aligned
  int tid = threadIdx.x;
  int i  = tid >> 2;        // 0..63
  int jg = tid & 3;         // 0..3 (16 floats each)
  const float* src = w + ((size_t)c << 20) + (size_t)(dt * 64 + i) * 1024 + ot * 64 + jg * 16;
  #pragma unroll
  for (int q = 0; q < 4; ++q) {
    float4 v = *(const float4*)(src + q * 4);
    t[jg * 16 + q * 4 + 0][i] = f2bf(v.x);
    t[jg * 16 + q * 4 + 1][i] = f2bf(v.y);
    t[jg * 16 + q * 4 + 2][i] = f2bf(v.z);
    t[jg * 16 + q * 4 + 3][i] = f2bf(v.w);
  }
  __syncthreads();
  unsigned short* dst = wt + ((size_t)c << 20) + (size_t)(ot * 64 + i) * 1024 + dt * 64 + jg * 16;
  uint4 a = *(const uint4*)&t[i][jg * 16];
  uint4 b = *(const uint4*)&t[i][jg * 16 + 8];
  *(uint4*)dst = a;
  *(uint4*)(dst + 8) = b;
}

// ---------------- K3: grouped GEMM (m97 structure, 128x128x32) -------------
__global__ __launch_bounds__(256) void k_gemm(const unsigned short* __restrict__ xg,
    const unsigned short* __restrict__ wt, const float* __restrict__ bias,
    const int* __restrict__ row_token, const int* __restrict__ tile_c,
    const int* __restrict__ tile_m, float* __restrict__ out) {
  int mt = blockIdx.y;
  int c = tile_c[mt];
  if (c < 0) return;
  int m0 = tile_m[mt];
  int n0 = blockIdx.x * BN;

  __shared__ unsigned short As[BM][BK];
  __shared__ unsigned short Bs[BN][BK];

  int tid  = threadIdx.x;
  int lane = tid & 63;
  int wave = tid >> 6;
  int wr = wave >> 1, wc = wave & 1;    // 2x2 waves, 64x64 each

  f32x4 acc[4][4];
  #pragma unroll
  for (int m = 0; m < 4; ++m)
    #pragma unroll
    for (int n = 0; n < 4; ++n) acc[m][n] = (f32x4){0.f, 0.f, 0.f, 0.f};

  const unsigned short* Ag = xg + (size_t)m0 * DIM;
  const unsigned short* Bg = wt + ((size_t)c << 20) + (size_t)n0 * DIM;
  int srow = tid >> 2;            // 0..63
  int scol = (tid & 3) << 3;      // 0,8,16,24

  for (int kt = 0; kt < DIM; kt += BK) {
    __syncthreads();
    __builtin_amdgcn_global_load_lds(
      (const __attribute__((address_space(1))) unsigned int*)(Ag + (size_t)srow * DIM + kt + scol),
      (__attribute__((address_space(3))) unsigned int*)(&As[srow][scol]), 16, 0, 0);
    __builtin_amdgcn_global_load_lds(
      (const __attribute__((address_space(1))) unsigned int*)(Ag + (size_t)(srow + 64) * DIM + kt + scol),
      (__attribute__((address_space(3))) unsigned int*)(&As[srow + 64][scol]), 16, 0, 0);
    __builtin_amdgcn_global_load_lds(
      (const __attribute__((address_space(1))) unsigned int*)(Bg + (size_t)srow * DIM + kt + scol),
      (__attribute__((address_space(3))) unsigned int*)(&Bs[srow][scol]), 16, 0, 0);
    __builtin_amdgcn_global_load_lds(
      (const __attribute__((address_space(1))) unsigned int*)(Bg + (size_t)(srow + 64) * DIM + kt + scol),
      (__attribute__((address_space(3))) unsigned int*)(&Bs[srow + 64][scol]), 16, 0, 0);
    __syncthreads();

    bf16x8 a[4], b[4];
    #pragma unroll
    for (int m = 0; m < 4; ++m)
      a[m] = *(const bf16x8*)&As[wr * 64 + m * 16 + (lane & 15)][(lane >> 4) * 8];
    #pragma unroll
    for (int n = 0; n < 4; ++n)
      b[n] = *(const bf16x8*)&Bs[wc * 64 + n * 16 + (lane & 15)][(lane >> 4) * 8];
    #pragma unroll
    for (int m = 0; m < 4; ++m)
      #pragma unroll
      for (int n = 0; n < 4; ++n)
        acc[m][n] = __builtin_amdgcn_mfma_f32_16x16x32_bf16(a[m], b[n], acc[m][n], 0, 0, 0);
  }

  int col = lane & 15;
  int rq  = (lane >> 4) << 2;
  float bv[4];
  #pragma unroll
  for (int n = 0; n < 4; ++n) bv[n] = bias[c * OUTD + n0 + wc * 64 + n * 16 + col];
  #pragma unroll
  for (int m = 0; m < 4; ++m) {
    #pragma unroll
    for (int r = 0; r < 4; ++r) {
      int prow = m0 + wr * 64 + m * 16 + rq + r;
      int tok = row_token[prow];
      if (tok < 0) continue;
      float* orow = out + (size_t)tok * OUTD + n0 + wc * 64 + col;
      #pragma unroll
      for (int n = 0; n < 4; ++n) orow[n * 16] = acc[m][n][r] + bv[n];
    }
  }
}

// ---------------- launcher -------------------------------------------------
extern "C" void kernel_launch(void* const* d_in, const int* in_sizes, int n_in,
                              void* d_out, int out_size, void* d_ws, size_t ws_size,
                              hipStream_t stream) {
  const float* x    = (const float*)d_in[0];
  const int*   cid  = (const int*)d_in[1];
  const float* w    = (const float*)d_in[2];
  const float* bias = (const float*)d_in[3];
  float* out = (float*)d_out;

  // workspace carve (~35.5 MB total)
  char* ws = (char*)d_ws;
  constexpr size_t XG_BYTES = (size_t)MPMAX * DIM * 2;          // 18,612,224
  constexpr size_t WT_BYTES = (size_t)NCAT * DIM * OUTD * 2;    // 16,777,216
  constexpr size_t RT_BYTES = (size_t)MPMAX * 4;                // 36,352
  unsigned short* xg  = (unsigned short*)ws;
  unsigned short* wtb = (unsigned short*)(ws + XG_BYTES);
  int* row_token = (int*)(ws + XG_BYTES + WT_BYTES);
  int* tile_c    = (int*)(ws + XG_BYTES + WT_BYTES + RT_BYTES);
  int* tile_m    = tile_c + MAX_MT;

  k_build<<<1, 1024, 0, stream>>>(cid, row_token, tile_c, tile_m);
  k_conv_w<<<dim3(16, 16, NCAT), 256, 0, stream>>>(w, wtb);
  k_gather_x<<<(MPMAX * (DIM / 8) + 255) / 256, 256, 0, stream>>>(x, row_token, xg);
  k_gemm<<<dim3(OUTD / BN, MAX_MT), 256, 0, stream>>>(xg, wtb, bias, row_token, tile_c, tile_m, out);
}